// Round 2
// baseline (255.627 us; speedup 1.0000x reference)
//
#include <hip/hip_runtime.h>
#include <math.h>

typedef __attribute__((ext_vector_type(8))) __bf16 bf16x8;
typedef __attribute__((ext_vector_type(4))) __bf16 bf16x4;
typedef __attribute__((ext_vector_type(4))) float floatx4;
typedef __attribute__((ext_vector_type(8))) float floatx8;

__device__ __forceinline__ float fast_rcp(float x) { return __builtin_amdgcn_rcpf(x); }
__device__ __forceinline__ float sigmoidf_(float z) { return fast_rcp(1.0f + __expf(-z)); }
__device__ __forceinline__ float fast_tanh(float z) {
    float e = __expf(2.0f * z);
    return 1.0f - 2.0f * fast_rcp(e + 1.0f);
}
__device__ __forceinline__ float leaky(float v) { return fmaxf(v, 0.01f * v); }

// XOR-swizzled byte offset into a [row][128B] LDS tile (conflict-free b128).
__device__ __forceinline__ int swzb(int row, int byteoff) {
    return row * 128 + (byteoff ^ ((row & 7) << 4));
}

// Direct global->LDS 16B per lane. LDS dest is wave-uniform base + lane*16
// (hardware layout); global address is per-lane (scattered allowed).
__device__ __forceinline__ void gload_lds16(const __bf16* g, char* l) {
    __builtin_amdgcn_global_load_lds((const __attribute__((address_space(1))) void*)g,
                                     (__attribute__((address_space(3))) void*)l, 16, 0, 0);
}

// ---- grid fp32 -> bf16 conversion into workspace ----
__global__ void convert_grids(const float* __restrict__ g0, const float* __restrict__ g1,
                              __bf16* __restrict__ o0, __bf16* __restrict__ o1, int elems) {
    int i = blockIdx.x * blockDim.x + threadIdx.x;
    int nvec = elems >> 2;
    if (i < nvec) {
        float4 v = ((const float4*)g0)[i];
        bf16x4 r = { (__bf16)v.x, (__bf16)v.y, (__bf16)v.z, (__bf16)v.w };
        ((bf16x4*)o0)[i] = r;
    } else if (i < 2 * nvec) {
        int j = i - nvec;
        float4 v = ((const float4*)g1)[j];
        bf16x4 r = { (__bf16)v.x, (__bf16)v.y, (__bf16)v.z, (__bf16)v.w };
        ((bf16x4*)o1)[j] = r;
    }
}

// 64 points per wave, lane = point for encoder/blend/epilogue.
// Gather phase (BF16G): 4-lane-cooperative corner loads via global_load_lds
// into wave-private double-buffered staging: per wave-instruction, lanes are
// (corner c = L>>4, chunk k = (L>>2)&3, point m = L&3) -> 16 contiguous 64B
// regions per instr (~16 cache lines) instead of 64 scattered lines with
// lane=point loads. Coords/weights reach loader lanes via packed-u32 shfl.
// Counted s_waitcnt vmcnt(4) pipelines iteration i+1's loads over blend(i).
// W1/W2/biases stay in LDS (round-1 regression: global wf loads shared the
// saturated vmem path and stalled the MFMAs).
// LDS: X 32K + stage 32K + W1 8K + W2 2K + biases = 74.3KB -> 2 blocks/CU.
template<bool BF16G>
__global__ __launch_bounds__(256, 2) void gridnet_fwd(
    const float2* __restrict__ pos, const float2* __restrict__ dir_,
    const float* __restrict__ pos_gridf, const float* __restrict__ dir_gridf,
    const __bf16* __restrict__ pos_gridb, const __bf16* __restrict__ dir_gridb,
    const float* __restrict__ enc_w1, const float* __restrict__ enc_b1,
    const float* __restrict__ enc_w2, const float* __restrict__ enc_b2,
    const float* __restrict__ fc_w1, const float* __restrict__ fc_b1,
    const float* __restrict__ fc_w2, const float* __restrict__ fc_b2,
    const float* __restrict__ fc_w3, const float* __restrict__ fc_b3,
    const float* __restrict__ fc_w4, const float* __restrict__ fc_b4,
    float* __restrict__ out, int n)
{
    // [0,32K) X tiles (wave w at w*8K, [64 pt][128B] swizzled)
    // [32K,64K) staging (wave w at 32K+w*8K; two 4KB buffers)
    // [64K,72K) W1 swizzled [64 out][128B]; [72K,74K) W2 swizzled [16][128B]
    __shared__ __align__(1024) char smem[32768 + 32768 + 8192 + 2048];
    __shared__ float b1lds[64];
    __shared__ float b2lds[16];

    const int tid  = threadIdx.x;
    const int lane = tid & 63;
    const int wid  = tid >> 6;
    const int quad = lane >> 4;
    const int l15  = lane & 15;

    char* Xw  = smem + wid * 8192;
    char* Stg = smem + 32768 + wid * 8192;
    char* W1p = smem + 65536;
    char* W2p = smem + 65536 + 8192;

    for (int idx = tid; idx < 4096; idx += 256)
        *(__bf16*)(W1p + swzb(idx & 63, (idx >> 6) * 2)) = (__bf16)fc_w1[idx];
    for (int idx = tid; idx < 1024; idx += 256)
        *(__bf16*)(W2p + swzb(idx & 15, (idx >> 4) * 2)) = (__bf16)fc_w2[idx];
    if (tid < 64) b1lds[tid] = fc_b1[tid];
    if (tid < 16) b2lds[tid] = fc_b2[tid];
    __syncthreads();

    int i  = blockIdx.x * 256 + wid * 64 + lane;
    int ic = min(i, n - 1);

    // ---- encoders for both passes; coords packed for shfl distribution ----
    unsigned pcp[2];
    float xfp[2], yfp[2];
    #pragma unroll
    for (int pass = 0; pass < 2; ++pass) {
        float2 xy = pass ? dir_[ic] : pos[ic];
        float hh[4];
        #pragma unroll
        for (int k = 0; k < 4; ++k)
            hh[k] = fast_tanh(xy.x * enc_w1[k] + xy.y * enc_w1[4 + k] + enc_b1[k]);
        float e0 = enc_b2[0], e1 = enc_b2[1];
        #pragma unroll
        for (int k = 0; k < 4; ++k) {
            e0 += hh[k] * enc_w2[3 * k + 0];
            e1 += hh[k] * enc_w2[3 * k + 1];
        }
        float x = sigmoidf_(e0) * 255.0f;
        float y = sigmoidf_(e1) * 255.0f;
        int x0 = (int)x, y0 = (int)y;
        xfp[pass] = x - (float)x0;
        yfp[pass] = y - (float)y0;
        int x1 = min(x0 + 1, 255), y1 = min(y0 + 1, 255);
        pcp[pass] = (unsigned)x0 | ((unsigned)y0 << 8) | ((unsigned)x1 << 16) | ((unsigned)y1 << 24);
    }

    if (BF16G) {
        const int m3 = lane & 3;          // issue role: point sub-index within instr
        const int ck = (lane >> 2) & 3;   // issue role: 16B chunk within corner
        const int cc = lane >> 4;         // issue role: corner (bit0: x1, bit1: y1)
        const int bq = lane >> 2;         // blend role: local point 0..15
        const int bk = lane & 3;          // blend role: chunk

        // prologue: issue iter 0 (pass 0, points 0..15) into buf 0
        {
            #pragma unroll
            for (int j = 0; j < 4; ++j) {
                unsigned pcq = (unsigned)__shfl((int)pcp[0], j * 4 + m3);
                int xq = (cc & 1) ? ((pcq >> 16) & 255) : (pcq & 255);
                int yq = (cc & 2) ? (int)(pcq >> 24) : (int)((pcq >> 8) & 255);
                gload_lds16(pos_gridb + ((yq << 8) + xq) * 32 + ck * 8, Stg + j * 1024);
            }
        }

        #pragma unroll
        for (int it = 0; it < 8; ++it) {
            const int pass = it >> 2, j16 = it & 3;
            const int buf = (it & 1) * 4096;
            // issue iter it+1 into the other buffer
            if (it < 7) {
                const int nit = it + 1, np = nit >> 2, nj16 = nit & 3;
                const __bf16* g = np ? dir_gridb : pos_gridb;
                #pragma unroll
                for (int j = 0; j < 4; ++j) {
                    unsigned pcq = (unsigned)__shfl((int)pcp[np], nj16 * 16 + j * 4 + m3);
                    int xq = (cc & 1) ? ((pcq >> 16) & 255) : (pcq & 255);
                    int yq = (cc & 2) ? (int)(pcq >> 24) : (int)((pcq >> 8) & 255);
                    gload_lds16(g + ((yq << 8) + xq) * 32 + ck * 8,
                                Stg + ((nit & 1) * 4096) + j * 1024);
                }
            }
            // weights of this iter's point (independent of the wait)
            float xfq = __shfl(xfp[pass], j16 * 16 + bq);
            float yfq = __shfl(yfp[pass], j16 * 16 + bq);
            float oxf = 1.0f - xfq, oyf = 1.0f - yfq;
            float w0 = oyf * oxf, w1 = oyf * xfq, w2 = yfq * oxf, w3 = yfq * xfq;

            if (it < 7) __asm__ volatile("s_waitcnt vmcnt(4)" ::: "memory");
            else        __asm__ volatile("s_waitcnt vmcnt(0)" ::: "memory");

            // staged layout within instr-block j: c*256 + k*64 + m*16
            const char* sb = Stg + buf + (lane >> 4) * 1024 + bk * 64 + ((lane >> 2) & 3) * 16;
            bf16x8 c0 = *(const bf16x8*)(sb + 0);
            bf16x8 c1 = *(const bf16x8*)(sb + 256);
            bf16x8 c2 = *(const bf16x8*)(sb + 512);
            bf16x8 c3 = *(const bf16x8*)(sb + 768);
            floatx8 r = w0 * __builtin_convertvector(c0, floatx8)
                      + w1 * __builtin_convertvector(c1, floatx8)
                      + w2 * __builtin_convertvector(c2, floatx8)
                      + w3 * __builtin_convertvector(c3, floatx8);
            int q = j16 * 16 + bq;
            *(bf16x8*)(Xw + swzb(q, pass * 64 + bk * 16)) = __builtin_convertvector(r, bf16x8);
        }
    } else {
        // fallback: per-lane fp32 gather (workspace too small for bf16 grids)
        #pragma unroll
        for (int pass = 0; pass < 2; ++pass) {
            const float* g = pass ? dir_gridf : pos_gridf;
            unsigned pcq = pcp[pass];
            int x0 = pcq & 255, y0 = (pcq >> 8) & 255, x1 = (pcq >> 16) & 255, y1 = pcq >> 24;
            float xfq = xfp[pass], yfq = yfp[pass];
            float oxf = 1.0f - xfq, oyf = 1.0f - yfq;
            float w0 = oyf * oxf, w1 = oyf * xfq, w2 = yfq * oxf, w3 = yfq * xfq;
            int ctl = ((y0 << 8) + x0) << 5, ctr = ((y0 << 8) + x1) << 5;
            int cbl = ((y1 << 8) + x0) << 5, cbr = ((y1 << 8) + x1) << 5;
            #pragma unroll
            for (int c = 0; c < 4; ++c) {
                floatx8 fa = *(const floatx8*)(g + ctl + c * 8);
                floatx8 fb = *(const floatx8*)(g + ctr + c * 8);
                floatx8 fc = *(const floatx8*)(g + cbl + c * 8);
                floatx8 fd = *(const floatx8*)(g + cbr + c * 8);
                floatx8 r = w0 * fa + w1 * fb + w2 * fc + w3 * fd;
                *(bf16x8*)(Xw + swzb(lane, pass * 64 + c * 16)) = __builtin_convertvector(r, bf16x8);
            }
        }
    }

    __asm__ volatile("s_waitcnt lgkmcnt(0)" ::: "memory");

    // ---- W1 fragments from LDS ----
    bf16x8 wf[2][4];
    #pragma unroll
    for (int ks = 0; ks < 2; ++ks)
        #pragma unroll
        for (int mt = 0; mt < 4; ++mt)
            wf[ks][mt] = *(const bf16x8*)(W1p + swzb(mt * 16 + l15, ks * 64 + quad * 16));

    floatx4 b1v[4];
    #pragma unroll
    for (int mt = 0; mt < 4; ++mt)
        b1v[mt] = *(const floatx4*)(b1lds + mt * 16 + quad * 4);

    // ---- fc1: D[out 64][pt 64] = W1 * X^T : 32 MFMAs ----
    floatx4 acc[4][4];
    #pragma unroll
    for (int mt = 0; mt < 4; ++mt)
        #pragma unroll
        for (int nt = 0; nt < 4; ++nt)
            acc[mt][nt] = b1v[mt];

    #pragma unroll
    for (int ks = 0; ks < 2; ++ks) {
        bf16x8 xf[4];
        #pragma unroll
        for (int nt = 0; nt < 4; ++nt)
            xf[nt] = *(const bf16x8*)(Xw + swzb(nt * 16 + l15, ks * 64 + quad * 16));
        #pragma unroll
        for (int mt = 0; mt < 4; ++mt)
            #pragma unroll
            for (int nt = 0; nt < 4; ++nt)
                acc[mt][nt] = __builtin_amdgcn_mfma_f32_16x16x32_bf16(wf[ks][mt], xf[nt], acc[mt][nt], 0, 0, 0);
    }

    // writeback h1: lane holds feats (mt*16+quad*4 .. +3) of pt (nt*16+l15)
    #pragma unroll
    for (int mt = 0; mt < 4; ++mt)
        #pragma unroll
        for (int nt = 0; nt < 4; ++nt) {
            bf16x4 hv;
            #pragma unroll
            for (int r = 0; r < 4; ++r)
                hv[r] = (__bf16)leaky(acc[mt][nt][r]);
            *(bf16x4*)(Xw + swzb(nt * 16 + l15, mt * 32 + quad * 8)) = hv;
        }
    __asm__ volatile("s_waitcnt lgkmcnt(0)" ::: "memory");

    // ---- fc2: D[out 16][pt 64] : 8 MFMAs ----
    bf16x8 w2f[2];
    #pragma unroll
    for (int ks = 0; ks < 2; ++ks)
        w2f[ks] = *(const bf16x8*)(W2p + swzb(l15, ks * 64 + quad * 16));
    floatx4 b2v = *(const floatx4*)(b2lds + quad * 4);
    floatx4 acc2[4];
    #pragma unroll
    for (int nt = 0; nt < 4; ++nt) acc2[nt] = b2v;
    #pragma unroll
    for (int ks = 0; ks < 2; ++ks) {
        #pragma unroll
        for (int nt = 0; nt < 4; ++nt) {
            bf16x8 hf = *(const bf16x8*)(Xw + swzb(nt * 16 + l15, ks * 64 + quad * 16));
            acc2[nt] = __builtin_amdgcn_mfma_f32_16x16x32_bf16(w2f[ks], hf, acc2[nt], 0, 0, 0);
        }
    }

    // writeback h2 fp32: [pt][16 f32] at swizzled 16B slots -> b128 stores
    #pragma unroll
    for (int nt = 0; nt < 4; ++nt) {
        floatx4 hv;
        #pragma unroll
        for (int r = 0; r < 4; ++r)
            hv[r] = leaky(acc2[nt][r]);
        *(floatx4*)(Xw + swzb(nt * 16 + l15, quad * 16)) = hv;
    }
    __asm__ volatile("s_waitcnt lgkmcnt(0)" ::: "memory");

    // ---- fc3/fc4 per lane (lane = point), sigmoid, store ----
    float h2[16];
    #pragma unroll
    for (int c = 0; c < 4; ++c) {
        floatx4 v = *(const floatx4*)(Xw + swzb(lane, c * 16));
        h2[4 * c + 0] = v[0]; h2[4 * c + 1] = v[1]; h2[4 * c + 2] = v[2]; h2[4 * c + 3] = v[3];
    }
    float h3[8];
    #pragma unroll
    for (int j = 0; j < 8; ++j) h3[j] = fc_b3[j];
    #pragma unroll
    for (int k = 0; k < 16; ++k) {
        float xv = h2[k];
        #pragma unroll
        for (int j = 0; j < 8; ++j) h3[j] = fmaf(xv, fc_w3[(k << 3) + j], h3[j]);
    }
    #pragma unroll
    for (int j = 0; j < 8; ++j) h3[j] = leaky(h3[j]);

    float o[3];
    #pragma unroll
    for (int j = 0; j < 3; ++j) o[j] = fc_b4[j];
    #pragma unroll
    for (int k = 0; k < 8; ++k) {
        float xv = h3[k];
        #pragma unroll
        for (int j = 0; j < 3; ++j) o[j] = fmaf(xv, fc_w4[3 * k + j], o[j]);
    }
    if (i < n) {
        #pragma unroll
        for (int j = 0; j < 3; ++j)
            out[3 * i + j] = sigmoidf_(leaky(o[j])) * 255.0f;
    }
}

extern "C" void kernel_launch(void* const* d_in, const int* in_sizes, int n_in,
                              void* d_out, int out_size, void* d_ws, size_t ws_size,
                              hipStream_t stream) {
    int n = in_sizes[0] / 2;  // pos is [N,2]
    const int GELEMS = 256 * 256 * 32;
    bool use_bf16 = ws_size >= (size_t)(2 * GELEMS * sizeof(__bf16));
    __bf16* g0 = (__bf16*)d_ws;
    __bf16* g1 = g0 + GELEMS;

    if (use_bf16) {
        int total = 2 * (GELEMS / 4);
        convert_grids<<<(total + 255) / 256, 256, 0, stream>>>(
            (const float*)d_in[2], (const float*)d_in[3], g0, g1, GELEMS);
    }

    int blocks = (n + 255) / 256;
    if (use_bf16) {
        gridnet_fwd<true><<<blocks, 256, 0, stream>>>(
            (const float2*)d_in[0], (const float2*)d_in[1],
            (const float*)d_in[2], (const float*)d_in[3], g0, g1,
            (const float*)d_in[4], (const float*)d_in[5],
            (const float*)d_in[6], (const float*)d_in[7],
            (const float*)d_in[8], (const float*)d_in[9],
            (const float*)d_in[10], (const float*)d_in[11],
            (const float*)d_in[12], (const float*)d_in[13],
            (const float*)d_in[14], (const float*)d_in[15],
            (float*)d_out, n);
    } else {
        gridnet_fwd<false><<<blocks, 256, 0, stream>>>(
            (const float2*)d_in[0], (const float2*)d_in[1],
            (const float*)d_in[2], (const float*)d_in[3], g0, g1,
            (const float*)d_in[4], (const float*)d_in[5],
            (const float*)d_in[6], (const float*)d_in[7],
            (const float*)d_in[8], (const float*)d_in[9],
            (const float*)d_in[10], (const float*)d_in[11],
            (const float*)d_in[12], (const float*)d_in[13],
            (const float*)d_in[14], (const float*)d_in[15],
            (float*)d_out, n);
    }
}

// Round 3
// 217.974 us; speedup vs baseline: 1.1727x; 1.1727x over previous
//
#include <hip/hip_runtime.h>
#include <math.h>

typedef __attribute__((ext_vector_type(8))) __bf16 bf16x8;
typedef __attribute__((ext_vector_type(4))) __bf16 bf16x4;
typedef __attribute__((ext_vector_type(4))) float floatx4;
typedef __attribute__((ext_vector_type(8))) float floatx8;

__device__ __forceinline__ float fast_rcp(float x) { return __builtin_amdgcn_rcpf(x); }
__device__ __forceinline__ float sigmoidf_(float z) { return fast_rcp(1.0f + __expf(-z)); }
__device__ __forceinline__ float fast_tanh(float z) {
    float e = __expf(2.0f * z);
    return 1.0f - 2.0f * fast_rcp(e + 1.0f);
}
__device__ __forceinline__ float leaky(float v) { return fmaxf(v, 0.01f * v); }

// XOR-swizzled byte offset into a [row][128B] LDS tile (conflict-free b64/b128;
// 128B stride alone would put all rows' col-k in the same bank).
__device__ __forceinline__ int swzb(int row, int byteoff) {
    return row * 128 + (byteoff ^ ((row & 7) << 4));
}

// ---- grid fp32 -> bf16 conversion into workspace ----
__global__ void convert_grids(const float* __restrict__ g0, const float* __restrict__ g1,
                              __bf16* __restrict__ o0, __bf16* __restrict__ o1, int elems) {
    int i = blockIdx.x * blockDim.x + threadIdx.x;
    int nvec = elems >> 2;
    if (i < nvec) {
        float4 v = ((const float4*)g0)[i];
        bf16x4 r = { (__bf16)v.x, (__bf16)v.y, (__bf16)v.z, (__bf16)v.w };
        ((bf16x4*)o0)[i] = r;
    } else if (i < 2 * nvec) {
        int j = i - nvec;
        float4 v = ((const float4*)g1)[j];
        bf16x4 r = { (__bf16)v.x, (__bf16)v.y, (__bf16)v.z, (__bf16)v.w };
        ((bf16x4*)o1)[j] = r;
    }
}

// 64 points per wave; lane = point for encoder and fc3/fc4 epilogue.
// Blend phase is fragment-mapped: lane (quad,l15) blends the 8-feature chunk
// `quad` of points {nt*16+l15} for both passes -- exactly its fc1 MFMA
// B-fragment, so X never touches LDS (r0 spent 16 b128 ds ops + 2 lgkm drains
// + ~8.5M conflict cycles on the X round-trip). Coords/fractions of the
// target point arrive via 3 shfls per (pass,nt). Each gather instruction now
// covers 16 corner regions (4 quads x 16 pts) instead of 64 -- coalescing
// gain with no staging machinery (r2's mistake).
// W1/W2/biases stay in LDS (r1 regression: global W loads added ~30% more
// scattered-vmem lane-slots); wf/b1v LDS reads hoisted above the gather so
// the LDS pipe runs during the vmem stall.
// LDS: h1/h2 scratch 4x8K + W1 8K + W2 2K + biases = 42.6KB -> 3 blocks/CU.
template<bool BF16G>
__global__ __launch_bounds__(256, 3) void gridnet_fwd(
    const float2* __restrict__ pos, const float2* __restrict__ dir_,
    const float* __restrict__ pos_gridf, const float* __restrict__ dir_gridf,
    const __bf16* __restrict__ pos_gridb, const __bf16* __restrict__ dir_gridb,
    const float* __restrict__ enc_w1, const float* __restrict__ enc_b1,
    const float* __restrict__ enc_w2, const float* __restrict__ enc_b2,
    const float* __restrict__ fc_w1, const float* __restrict__ fc_b1,
    const float* __restrict__ fc_w2, const float* __restrict__ fc_b2,
    const float* __restrict__ fc_w3, const float* __restrict__ fc_b3,
    const float* __restrict__ fc_w4, const float* __restrict__ fc_b4,
    float* __restrict__ out, int n)
{
    // [0,32K) h1/h2 scratch (wave w at w*8K, [64 pt][128B] swizzled)
    // [32K,40K) W1 swizzled [64 out][128B]; [40K,42K) W2 swizzled [16][128B]
    __shared__ __align__(1024) char smem[32768 + 8192 + 2048];
    __shared__ float b1lds[64];
    __shared__ float b2lds[16];

    const int tid  = threadIdx.x;
    const int lane = tid & 63;
    const int wid  = tid >> 6;
    const int quad = lane >> 4;
    const int l15  = lane & 15;

    char* Hw  = smem + wid * 8192;
    char* W1p = smem + 32768;
    char* W2p = smem + 32768 + 8192;

    for (int idx = tid; idx < 4096; idx += 256)
        *(__bf16*)(W1p + swzb(idx & 63, (idx >> 6) * 2)) = (__bf16)fc_w1[idx];
    for (int idx = tid; idx < 1024; idx += 256)
        *(__bf16*)(W2p + swzb(idx & 15, (idx >> 4) * 2)) = (__bf16)fc_w2[idx];
    if (tid < 64) b1lds[tid] = fc_b1[tid];
    if (tid < 16) b2lds[tid] = fc_b2[tid];
    __syncthreads();

    // hoisted: W1 A-fragments + fc1 bias (LDS pipe busy while gathers fly)
    bf16x8 wf[2][4];
    #pragma unroll
    for (int ks = 0; ks < 2; ++ks)
        #pragma unroll
        for (int mt = 0; mt < 4; ++mt)
            wf[ks][mt] = *(const bf16x8*)(W1p + swzb(mt * 16 + l15, ks * 64 + quad * 16));
    floatx4 b1v[4];
    #pragma unroll
    for (int mt = 0; mt < 4; ++mt)
        b1v[mt] = *(const floatx4*)(b1lds + mt * 16 + quad * 4);

    int i  = blockIdx.x * 256 + wid * 64 + lane;
    int ic = min(i, n - 1);

    // ---- encoders for both passes; coords packed for shfl distribution ----
    unsigned pcp[2];
    float xfp[2], yfp[2];
    #pragma unroll
    for (int pass = 0; pass < 2; ++pass) {
        float2 xy = pass ? dir_[ic] : pos[ic];
        float hh[4];
        #pragma unroll
        for (int k = 0; k < 4; ++k)
            hh[k] = fast_tanh(xy.x * enc_w1[k] + xy.y * enc_w1[4 + k] + enc_b1[k]);
        float e0 = enc_b2[0], e1 = enc_b2[1];
        #pragma unroll
        for (int k = 0; k < 4; ++k) {
            e0 += hh[k] * enc_w2[3 * k + 0];
            e1 += hh[k] * enc_w2[3 * k + 1];
        }
        float x = sigmoidf_(e0) * 255.0f;
        float y = sigmoidf_(e1) * 255.0f;
        int x0 = (int)x, y0 = (int)y;
        xfp[pass] = x - (float)x0;
        yfp[pass] = y - (float)y0;
        int x1 = min(x0 + 1, 255), y1 = min(y0 + 1, 255);
        pcp[pass] = (unsigned)x0 | ((unsigned)y0 << 8) | ((unsigned)x1 << 16) | ((unsigned)y1 << 24);
    }

    // ---- gather + blend straight into fc1 B-fragments (registers) ----
    // xfr[ks][nt] = X[pt = nt*16+l15][feats ks*32 + quad*8 .. +7]
    bf16x8 xfr[2][4];
    #pragma unroll
    for (int ks = 0; ks < 2; ++ks) {
        #pragma unroll
        for (int nt = 0; nt < 4; ++nt) {
            const int src = nt * 16 + l15;
            unsigned pcq = (unsigned)__shfl((int)pcp[ks], src);
            float xfq = __shfl(xfp[ks], src);
            float yfq = __shfl(yfp[ks], src);
            int x0 = pcq & 255, y0 = (pcq >> 8) & 255;
            int x1 = (pcq >> 16) & 255, y1 = pcq >> 24;
            float oxf = 1.0f - xfq, oyf = 1.0f - yfq;
            floatx8 r;
            if (BF16G) {
                const __bf16* ga = (ks ? dir_gridb : pos_gridb) + quad * 8;
                bf16x8 va = *(const bf16x8*)(ga + (((y0 << 8) + x0) << 5));
                bf16x8 vb = *(const bf16x8*)(ga + (((y0 << 8) + x1) << 5));
                bf16x8 vc = *(const bf16x8*)(ga + (((y1 << 8) + x0) << 5));
                bf16x8 vd = *(const bf16x8*)(ga + (((y1 << 8) + x1) << 5));
                r = (oyf * oxf) * __builtin_convertvector(va, floatx8)
                  + (oyf * xfq) * __builtin_convertvector(vb, floatx8)
                  + (yfq * oxf) * __builtin_convertvector(vc, floatx8)
                  + (yfq * xfq) * __builtin_convertvector(vd, floatx8);
            } else {
                const float* ga = (ks ? dir_gridf : pos_gridf) + quad * 8;
                floatx8 va = *(const floatx8*)(ga + (((y0 << 8) + x0) << 5));
                floatx8 vb = *(const floatx8*)(ga + (((y0 << 8) + x1) << 5));
                floatx8 vc = *(const floatx8*)(ga + (((y1 << 8) + x0) << 5));
                floatx8 vd = *(const floatx8*)(ga + (((y1 << 8) + x1) << 5));
                r = (oyf * oxf) * va + (oyf * xfq) * vb + (yfq * oxf) * vc + (yfq * xfq) * vd;
            }
            xfr[ks][nt] = __builtin_convertvector(r, bf16x8);
        }
    }

    // ---- fc1: D[out 64][pt 64] = W1 * X^T : 32 MFMAs, all-register operands ----
    floatx4 acc[4][4];
    #pragma unroll
    for (int mt = 0; mt < 4; ++mt)
        #pragma unroll
        for (int nt = 0; nt < 4; ++nt)
            acc[mt][nt] = b1v[mt];
    #pragma unroll
    for (int ks = 0; ks < 2; ++ks)
        #pragma unroll
        for (int mt = 0; mt < 4; ++mt)
            #pragma unroll
            for (int nt = 0; nt < 4; ++nt)
                acc[mt][nt] = __builtin_amdgcn_mfma_f32_16x16x32_bf16(wf[ks][mt], xfr[ks][nt], acc[mt][nt], 0, 0, 0);

    // writeback h1: lane holds feats (mt*16+quad*4 .. +3) of pt (nt*16+l15)
    #pragma unroll
    for (int mt = 0; mt < 4; ++mt)
        #pragma unroll
        for (int nt = 0; nt < 4; ++nt) {
            bf16x4 hv;
            #pragma unroll
            for (int r = 0; r < 4; ++r)
                hv[r] = (__bf16)leaky(acc[mt][nt][r]);
            *(bf16x4*)(Hw + swzb(nt * 16 + l15, mt * 32 + quad * 8)) = hv;
        }
    __asm__ volatile("s_waitcnt lgkmcnt(0)" ::: "memory");

    // ---- fc2: D[out 16][pt 64] : 8 MFMAs ----
    bf16x8 w2f[2];
    #pragma unroll
    for (int ks = 0; ks < 2; ++ks)
        w2f[ks] = *(const bf16x8*)(W2p + swzb(l15, ks * 64 + quad * 16));
    floatx4 b2v = *(const floatx4*)(b2lds + quad * 4);
    floatx4 acc2[4];
    #pragma unroll
    for (int nt = 0; nt < 4; ++nt) acc2[nt] = b2v;
    #pragma unroll
    for (int ks = 0; ks < 2; ++ks) {
        #pragma unroll
        for (int nt = 0; nt < 4; ++nt) {
            bf16x8 hf = *(const bf16x8*)(Hw + swzb(nt * 16 + l15, ks * 64 + quad * 16));
            acc2[nt] = __builtin_amdgcn_mfma_f32_16x16x32_bf16(w2f[ks], hf, acc2[nt], 0, 0, 0);
        }
    }

    // writeback h2 fp32: lane holds feats (quad*4..+3) of pt (nt*16+l15)
    #pragma unroll
    for (int nt = 0; nt < 4; ++nt) {
        floatx4 hv;
        #pragma unroll
        for (int r = 0; r < 4; ++r)
            hv[r] = leaky(acc2[nt][r]);
        *(floatx4*)(Hw + swzb(nt * 16 + l15, quad * 16)) = hv;
    }
    __asm__ volatile("s_waitcnt lgkmcnt(0)" ::: "memory");

    // ---- fc3/fc4 per lane (lane = point), sigmoid, store ----
    float h2[16];
    #pragma unroll
    for (int c = 0; c < 4; ++c) {
        floatx4 v = *(const floatx4*)(Hw + swzb(lane, c * 16));
        h2[4 * c + 0] = v[0]; h2[4 * c + 1] = v[1]; h2[4 * c + 2] = v[2]; h2[4 * c + 3] = v[3];
    }
    float h3[8];
    #pragma unroll
    for (int j = 0; j < 8; ++j) h3[j] = fc_b3[j];
    #pragma unroll
    for (int k = 0; k < 16; ++k) {
        float xv = h2[k];
        #pragma unroll
        for (int j = 0; j < 8; ++j) h3[j] = fmaf(xv, fc_w3[(k << 3) + j], h3[j]);
    }
    #pragma unroll
    for (int j = 0; j < 8; ++j) h3[j] = leaky(h3[j]);

    float o[3];
    #pragma unroll
    for (int j = 0; j < 3; ++j) o[j] = fc_b4[j];
    #pragma unroll
    for (int k = 0; k < 8; ++k) {
        float xv = h3[k];
        #pragma unroll
        for (int j = 0; j < 3; ++j) o[j] = fmaf(xv, fc_w4[3 * k + j], o[j]);
    }
    if (i < n) {
        #pragma unroll
        for (int j = 0; j < 3; ++j)
            out[3 * i + j] = sigmoidf_(leaky(o[j])) * 255.0f;
    }
}

extern "C" void kernel_launch(void* const* d_in, const int* in_sizes, int n_in,
                              void* d_out, int out_size, void* d_ws, size_t ws_size,
                              hipStream_t stream) {
    int n = in_sizes[0] / 2;  // pos is [N,2]
    const int GELEMS = 256 * 256 * 32;
    bool use_bf16 = ws_size >= (size_t)(2 * GELEMS * sizeof(__bf16));
    __bf16* g0 = (__bf16*)d_ws;
    __bf16* g1 = g0 + GELEMS;

    if (use_bf16) {
        int total = 2 * (GELEMS / 4);
        convert_grids<<<(total + 255) / 256, 256, 0, stream>>>(
            (const float*)d_in[2], (const float*)d_in[3], g0, g1, GELEMS);
    }

    int blocks = (n + 255) / 256;
    if (use_bf16) {
        gridnet_fwd<true><<<blocks, 256, 0, stream>>>(
            (const float2*)d_in[0], (const float2*)d_in[1],
            (const float*)d_in[2], (const float*)d_in[3], g0, g1,
            (const float*)d_in[4], (const float*)d_in[5],
            (const float*)d_in[6], (const float*)d_in[7],
            (const float*)d_in[8], (const float*)d_in[9],
            (const float*)d_in[10], (const float*)d_in[11],
            (const float*)d_in[12], (const float*)d_in[13],
            (const float*)d_in[14], (const float*)d_in[15],
            (float*)d_out, n);
    } else {
        gridnet_fwd<false><<<blocks, 256, 0, stream>>>(
            (const float2*)d_in[0], (const float2*)d_in[1],
            (const float*)d_in[2], (const float*)d_in[3], g0, g1,
            (const float*)d_in[4], (const float*)d_in[5],
            (const float*)d_in[6], (const float*)d_in[7],
            (const float*)d_in[8], (const float*)d_in[9],
            (const float*)d_in[10], (const float*)d_in[11],
            (const float*)d_in[12], (const float*)d_in[13],
            (const float*)d_in[14], (const float*)d_in[15],
            (float*)d_out, n);
    }
}